// Round 10
// baseline (1150.885 us; speedup 1.0000x reference)
//
#include <hip/hip_runtime.h>
#include <hip/hip_bf16.h>
#include <math.h>

#define NTOK   4096
#define DMODEL 1024
#define SEQL   2048
#define QKVW   1152     // 1024 q + 64 k + 64 v
#define NH     16
#define HDIM   64
#define NE     8
#define HIDD   4096
#define EPSV   1e-5f
#define KT     32       // attention kv-tile

// fp16 scales: activations *2^8, weights *2^12; folded out via OUTSCL.
// P scaled 2^15 via PBIAS; defer-max THR=0.5 keeps p_bar <= 2^15*e^0.5 = 54k < 65504.
#define ASCL   256.f
#define WSCL   4096.f
#define OUTSCL (1.f/1048576.f)          // 2^-20
#define SSCALE (0.125f/65536.f)         // 1/sqrt(64) * 2^-16 (Q,K both *2^8)
#define PBIAS  10.397207708399179f      // 15*ln2 -> P scaled 2^15
#define DTHR   0.5f                     // defer-max threshold (fp16-P overflow-safe)

typedef __attribute__((ext_vector_type(8))) short bf16x8;
typedef __attribute__((ext_vector_type(8))) _Float16 f16x8;
typedef __attribute__((ext_vector_type(4))) _Float16 f16x4;
typedef __attribute__((ext_vector_type(4))) float f32x4;

#define GLOBAL_AS __attribute__((address_space(1)))
#define LDS_AS    __attribute__((address_space(3)))
__device__ __forceinline__ void gl_lds16(const void* g, void* l){
  __builtin_amdgcn_global_load_lds((const GLOBAL_AS void*)g, (LDS_AS void*)l, 16u, 0, 0u);
}

__device__ __forceinline__ short f2b(float x){
  __hip_bfloat16 h = __float2bfloat16(x);
  return *reinterpret_cast<short*>(&h);
}
__device__ __forceinline__ void split2h(float x, _Float16& a, _Float16& b){
  a = (_Float16)x;
  b = (_Float16)(x - (float)a);
}

// ---------------- transpose fp32 [R][C] -> bf16 [C][R] (expert weights), short4 stores ----------------
__global__ __launch_bounds__(256) void transpose_conv_kernel(
    const float* __restrict__ in, short* __restrict__ out,
    int R, int C, long inb, long outb)
{
  __shared__ float tile[32][33];
  in  += (size_t)blockIdx.z * inb;
  out += (size_t)blockIdx.z * outb;
  int c0 = blockIdx.x*32, r0 = blockIdx.y*32;
  int tx = threadIdx.x & 31, ty = threadIdx.x >> 5;
  #pragma unroll
  for (int i=0;i<4;i++)
    tile[ty+i*8][tx] = in[(size_t)(r0+ty+i*8)*C + c0+tx];   // tile[r][c]
  __syncthreads();
  int cl = threadIdx.x >> 3, quad = threadIdx.x & 7;
  short4 s;
  s.x = f2b(tile[quad*4+0][cl]);
  s.y = f2b(tile[quad*4+1][cl]);
  s.z = f2b(tile[quad*4+2][cl]);
  s.w = f2b(tile[quad*4+3][cl]);
  *(short4*)&out[(size_t)(c0+cl)*R + r0 + quad*4] = s;
}

// ---------------- transpose fp32 [R][C] -> 2 fp16 planes [C+rowOff][outLD=R], *2^12 ----------------
__global__ __launch_bounds__(256) void transpose_split2f16_kernel(
    const float* __restrict__ in, _Float16* __restrict__ o1, _Float16* __restrict__ o2,
    int R, int C, int rowOff, int outLD)
{
  __shared__ float tile[32][33];
  int c0 = blockIdx.x*32, r0 = blockIdx.y*32;
  int tx = threadIdx.x & 31, ty = threadIdx.x >> 5;
  #pragma unroll
  for (int i=0;i<4;i++)
    tile[ty+i*8][tx] = in[(size_t)(r0+ty+i*8)*C + c0+tx];
  __syncthreads();
  #pragma unroll
  for (int i=0;i<4;i++){
    float v = tile[tx][ty+i*8] * WSCL;
    _Float16 va,vb; split2h(v,va,vb);
    size_t idx = (size_t)(c0+ty+i*8+rowOff)*outLD + r0+tx;
    o1[idx]=va; o2[idx]=vb;
  }
}

// ---------------- rmsnorm(x)*g*2^8 -> 2 fp16 planes ----------------
__global__ __launch_bounds__(256) void rms_split2_kernel(
    const float* __restrict__ x, const float* __restrict__ g,
    _Float16* __restrict__ o1, _Float16* __restrict__ o2)
{
  int row = blockIdx.x, tid = threadIdx.x;
  const float4* xr = (const float4*)(x + (size_t)row*DMODEL);
  float4 v = xr[tid];
  float ss = v.x*v.x + v.y*v.y + v.z*v.z + v.w*v.w;
  #pragma unroll
  for (int off=32; off; off>>=1) ss += __shfl_down(ss, off);
  __shared__ float red[4];
  if ((tid&63)==0) red[tid>>6] = ss;
  __syncthreads();
  float rs = rsqrtf((red[0]+red[1]+red[2]+red[3])*(1.f/1024.f) + EPSV) * ASCL;
  float4 gv = ((const float4*)g)[tid];
  float o[4] = {v.x*rs*gv.x, v.y*rs*gv.y, v.z*rs*gv.z, v.w*rs*gv.w};
  f16x4 s1,s2;
  #pragma unroll
  for (int c=0;c<4;c++){ _Float16 a,b; split2h(o[c],a,b); s1[c]=a; s2[c]=b; }
  size_t base = (size_t)row*DMODEL + tid*4;
  *(f16x4*)(o1+base) = s1; *(f16x4*)(o2+base) = s2;
}

// ---------------- V^T build from qkv fp16 planes -> vt fp16 planes [2][64][2048] ----------------
// planes already carry *2^8; no rescale. (r3 postmortem: never shadow the batch index.)
__global__ __launch_bounds__(256) void vtrans_split2_kernel(
    const _Float16* __restrict__ p1, const _Float16* __restrict__ p2,
    _Float16* __restrict__ o1, _Float16* __restrict__ o2)
{
  __shared__ float tile[32][33];
  int s0 = blockIdx.x*32, d0 = blockIdx.y*32, bb = blockIdx.z;
  int tx = threadIdx.x & 31, ty = threadIdx.x >> 5;
  #pragma unroll
  for (int i=0;i<4;i++){
    size_t idx = (size_t)(bb*SEQL + s0+ty+i*8)*QKVW + DMODEL+HDIM + d0+tx;
    tile[ty+i*8][tx] = (float)p1[idx] + (float)p2[idx];
  }
  __syncthreads();
  #pragma unroll
  for (int i=0;i<4;i++){
    float v = tile[tx][ty+i*8];          // [s=tx][d=ty+i*8], already *2^8
    _Float16 va,vb; split2h(v,va,vb);
    size_t idx = (size_t)(bb*HDIM + d0+ty+i*8)*SEQL + s0+tx;
    o1[idx]=va; o2[idx]=vb;
  }
}

// ---------------- fp32-accurate GEMM via 3-pass fp16x2 MFMA + global_load_lds ----------------
// grid: x = m-tiles (fastest) for B-tile L2 sharing across consecutive blocks.
__global__ __launch_bounds__(256) void gemm_f16x2_kernel(
    const _Float16* __restrict__ a1, const _Float16* __restrict__ a2,
    const _Float16* __restrict__ b1, const _Float16* __restrict__ b2,
    float* __restrict__ C, int K, int ldc, float outscale)
{
  __shared__ _Float16 lsA[2][128*32];
  __shared__ _Float16 lsB[2][128*32];
  int m0 = blockIdx.x*128, n0 = blockIdx.y*128;
  int tid = threadIdx.x, wave = tid>>6, lane = tid&63;
  int g = lane>>4, li = lane&15;
  int wm = (wave>>1)*64, wn = (wave&1)*64;
  const _Float16* Ap[2] = {a1,a2};
  const _Float16* Bp[2] = {b1,b2};
  int srow = wave*32 + (lane>>2), scol = (lane&3)*8;
  const _Float16* gA[2][2]; const _Float16* gB[2][2];
  #pragma unroll
  for (int p=0;p<2;p++)
    #pragma unroll
    for (int i=0;i<2;i++){
      gA[p][i] = Ap[p] + (size_t)(m0+srow+i*16)*K + scol;
      gB[p][i] = Bp[p] + (size_t)(n0+srow+i*16)*K + scol;
    }
  f32x4 acc[4][4] = {};
  for (int k0=0; k0<K; k0+=32){
    #pragma unroll
    for (int p=0;p<2;p++)
      #pragma unroll
      for (int i=0;i<2;i++){
        gl_lds16(gA[p][i]+k0, &lsA[p][(wave*32+i*16)*32]);
        gl_lds16(gB[p][i]+k0, &lsB[p][(wave*32+i*16)*32]);
      }
    __syncthreads();
    #pragma unroll
    for (int i=0;i<2;i++){
      f16x8 af[4];
      #pragma unroll
      for (int m=0;m<4;m++) af[m] = *(f16x8*)&lsA[i][(wm+m*16+li)*32 + g*8];
      #pragma unroll
      for (int j=0;j<2-i;j++){
        #pragma unroll
        for (int n=0;n<4;n++){
          f16x8 bfr = *(f16x8*)&lsB[j][(wn+n*16+li)*32 + g*8];
          #pragma unroll
          for (int m=0;m<4;m++)
            acc[m][n] = __builtin_amdgcn_mfma_f32_16x16x32_f16(af[m], bfr, acc[m][n], 0,0,0);
        }
      }
    }
    __syncthreads();
  }
  #pragma unroll
  for (int m=0;m<4;m++){
    int lr0 = wm + m*16 + g*4;
    #pragma unroll
    for (int n=0;n<4;n++){
      int col = n0 + wn + n*16 + li;
      #pragma unroll
      for (int r=0;r<4;r++)
        C[(size_t)(m0+lr0+r)*ldc + col] = acc[m][n][r]*outscale;
    }
  }
}

// ---------------- same GEMM, split-epilogue: writes 2 fp16 planes (for QKV) ----------------
__global__ __launch_bounds__(256) void gemm_f16x2s_kernel(
    const _Float16* __restrict__ a1, const _Float16* __restrict__ a2,
    const _Float16* __restrict__ b1, const _Float16* __restrict__ b2,
    _Float16* __restrict__ o1, _Float16* __restrict__ o2, int K, int ldc, float outscale)
{
  __shared__ _Float16 lsA[2][128*32];
  __shared__ _Float16 lsB[2][128*32];
  int m0 = blockIdx.x*128, n0 = blockIdx.y*128;
  int tid = threadIdx.x, wave = tid>>6, lane = tid&63;
  int g = lane>>4, li = lane&15;
  int wm = (wave>>1)*64, wn = (wave&1)*64;
  const _Float16* Ap[2] = {a1,a2};
  const _Float16* Bp[2] = {b1,b2};
  int srow = wave*32 + (lane>>2), scol = (lane&3)*8;
  const _Float16* gA[2][2]; const _Float16* gB[2][2];
  #pragma unroll
  for (int p=0;p<2;p++)
    #pragma unroll
    for (int i=0;i<2;i++){
      gA[p][i] = Ap[p] + (size_t)(m0+srow+i*16)*K + scol;
      gB[p][i] = Bp[p] + (size_t)(n0+srow+i*16)*K + scol;
    }
  f32x4 acc[4][4] = {};
  for (int k0=0; k0<K; k0+=32){
    #pragma unroll
    for (int p=0;p<2;p++)
      #pragma unroll
      for (int i=0;i<2;i++){
        gl_lds16(gA[p][i]+k0, &lsA[p][(wave*32+i*16)*32]);
        gl_lds16(gB[p][i]+k0, &lsB[p][(wave*32+i*16)*32]);
      }
    __syncthreads();
    #pragma unroll
    for (int i=0;i<2;i++){
      f16x8 af[4];
      #pragma unroll
      for (int m=0;m<4;m++) af[m] = *(f16x8*)&lsA[i][(wm+m*16+li)*32 + g*8];
      #pragma unroll
      for (int j=0;j<2-i;j++){
        #pragma unroll
        for (int n=0;n<4;n++){
          f16x8 bfr = *(f16x8*)&lsB[j][(wn+n*16+li)*32 + g*8];
          #pragma unroll
          for (int m=0;m<4;m++)
            acc[m][n] = __builtin_amdgcn_mfma_f32_16x16x32_f16(af[m], bfr, acc[m][n], 0,0,0);
        }
      }
    }
    __syncthreads();
  }
  #pragma unroll
  for (int m=0;m<4;m++){
    int lr0 = wm + m*16 + g*4;
    #pragma unroll
    for (int n=0;n<4;n++){
      int col = n0 + wn + n*16 + li;
      #pragma unroll
      for (int r=0;r<4;r++){
        float val = acc[m][n][r]*outscale;
        _Float16 xa,xb; split2h(val,xa,xb);
        size_t idx = (size_t)(m0+lr0+r)*ldc + col;
        o1[idx]=xa; o2[idx]=xb;
      }
    }
  }
}

// ---------------- flash attention: fp16x2 QK^T + fp16x2 PV, T14 async-stage, setprio ----------------
__global__ __launch_bounds__(256) void attn_f16_kernel(
    const _Float16* __restrict__ q1, const _Float16* __restrict__ q2,
    const _Float16* __restrict__ v1, const _Float16* __restrict__ v2,
    _Float16* __restrict__ o1, _Float16* __restrict__ o2)
{
  __shared__ _Float16 Ks[32*136];  // [kv][plane*64+d]
  __shared__ _Float16 Vs[64*72];   // [d][plane*32+kv]
  int qt = blockIdx.x, h = blockIdx.y, b = blockIdx.z;
  int tid = threadIdx.x, wave = tid>>6, lane = tid&63;
  int g = lane>>4, li = lane&15;
  size_t qbase = (size_t)b*SEQL + qt*128;
  const _Float16* qsrc[2] = {q1,q2};
  const _Float16* vsrc[2] = {v1,v2};
  f16x8 qf[2][2][2];
  #pragma unroll
  for (int nf=0;nf<2;nf++){
    size_t qrow = qbase + wave*32 + nf*16 + li;
    #pragma unroll
    for (int j=0;j<2;j++)
      #pragma unroll
      for (int kk=0;kk<2;kk++)
        qf[nf][j][kk] = *(const f16x8*)(qsrc[j] + qrow*QKVW + h*HDIM + kk*32 + g*8);
  }
  const _Float16* kga[2]; int klds[2];
  const _Float16* vga[2]; int vlds[2];
  #pragma unroll
  for (int i=0;i<2;i++){
    int c = tid + 256*i;
    { int row=c>>4, sub=c&15, pl=sub>>3, d=(sub&7)*8;
      kga[i] = qsrc[pl] + ((size_t)b*SEQL + row)*QKVW + DMODEL + d;
      klds[i] = row*136 + pl*64 + d; }
    { int row=c>>3, sub=c&7, pl=sub>>2, s8=(sub&3)*8;
      vga[i] = vsrc[pl] + ((size_t)b*HDIM + row)*SEQL + s8;
      vlds[i] = row*72 + pl*32 + s8; }
  }
  f16x8 kreg[2], vreg[2];
  #pragma unroll
  for (int i=0;i<2;i++){ kreg[i]=*(const f16x8*)kga[i]; vreg[i]=*(const f16x8*)vga[i]; }

  float m_run[2] = {-1e30f,-1e30f}, l_run[2] = {0.f,0.f};
  f32x4 acc_o[4][2] = {};
  int src1 = (((2*g)&3)<<4) + li;
  int src2 = (((2*g+1)&3)<<4) + li;
  bool hi_half = (g>=2);

  for (int kvt=0; kvt<SEQL/KT; kvt++){
    #pragma unroll
    for (int i=0;i<2;i++){
      *(f16x8*)&Ks[klds[i]] = kreg[i];
      *(f16x8*)&Vs[vlds[i]] = vreg[i];
    }
    __syncthreads();
    if (kvt+1 < SEQL/KT){
      #pragma unroll
      for (int i=0;i<2;i++){
        kreg[i] = *(const f16x8*)(kga[i] + (size_t)(kvt+1)*KT*QKVW);
        vreg[i] = *(const f16x8*)(vga[i] + (size_t)(kvt+1)*KT);
      }
    }
    f32x4 s_acc[2][2] = {};
    __builtin_amdgcn_s_setprio(1);
    #pragma unroll
    for (int i=0;i<2;i++){
      #pragma unroll
      for (int kk=0;kk<2;kk++){
        f16x8 af[2];
        #pragma unroll
        for (int mf=0;mf<2;mf++)
          af[mf] = *(f16x8*)&Ks[(mf*16+li)*136 + i*64 + kk*32 + g*8];
        #pragma unroll
        for (int j=0;j<2-i;j++){
          #pragma unroll
          for (int nf=0;nf<2;nf++){
            #pragma unroll
            for (int mf=0;mf<2;mf++)
              s_acc[mf][nf] = __builtin_amdgcn_mfma_f32_16x16x32_f16(af[mf], qf[nf][j][kk], s_acc[mf][nf], 0,0,0);
          }
        }
      }
    }
    __builtin_amdgcn_s_setprio(0);
    float p[2][2][4];
    #pragma unroll
    for (int nf=0;nf<2;nf++){
      float mx = -1e30f;
      #pragma unroll
      for (int mf=0;mf<2;mf++)
        #pragma unroll
        for (int r=0;r<4;r++) mx = fmaxf(mx, s_acc[mf][nf][r]);
      mx = fmaxf(mx, __shfl_xor(mx,16));
      mx = fmaxf(mx, __shfl_xor(mx,32));
      mx *= SSCALE;
      if (!__all(mx <= m_run[nf] + DTHR)){
        float mn = fmaxf(m_run[nf], mx);
        float al = __expf(m_run[nf] - mn);
        m_run[nf] = mn;
        l_run[nf] *= al;
        #pragma unroll
        for (int mfd=0; mfd<4; mfd++){
          acc_o[mfd][nf][0]*=al; acc_o[mfd][nf][1]*=al;
          acc_o[mfd][nf][2]*=al; acc_o[mfd][nf][3]*=al;
        }
      }
      float rsum = 0.f;
      #pragma unroll
      for (int mf=0;mf<2;mf++)
        #pragma unroll
        for (int r=0;r<4;r++){
          float pv = __expf(s_acc[mf][nf][r]*SSCALE - m_run[nf] + PBIAS);
          p[mf][nf][r] = pv; rsum += pv;
        }
      rsum += __shfl_xor(rsum,16);
      rsum += __shfl_xor(rsum,32);
      l_run[nf] += rsum;
    }
    f16x8 fp_frag[2][2];
    #pragma unroll
    for (int nf=0;nf<2;nf++){
      float p8[8];
      #pragma unroll
      for (int jj=0;jj<4;jj++){
        float v0 = __shfl(p[0][nf][jj], src1);
        float vv1 = __shfl(p[1][nf][jj], src1);
        p8[jj] = hi_half ? vv1 : v0;
        float w0 = __shfl(p[0][nf][jj], src2);
        float w1 = __shfl(p[1][nf][jj], src2);
        p8[4+jj] = hi_half ? w1 : w0;
      }
      #pragma unroll
      for (int jj=0;jj<8;jj++){
        _Float16 xa,xb; split2h(p8[jj], xa,xb);
        fp_frag[nf][0][jj]=xa; fp_frag[nf][1][jj]=xb;
      }
    }
    __builtin_amdgcn_s_setprio(1);
    #pragma unroll
    for (int vj=0;vj<2;vj++){
      f16x8 av[4];
      #pragma unroll
      for (int mfd=0;mfd<4;mfd++)
        av[mfd] = *(f16x8*)&Vs[(mfd*16+li)*72 + vj*32 + g*8];
      #pragma unroll
      for (int pi=0; pi<2-vj; pi++)
        #pragma unroll
        for (int mfd=0;mfd<4;mfd++)
          #pragma unroll
          for (int nf=0;nf<2;nf++)
            acc_o[mfd][nf] = __builtin_amdgcn_mfma_f32_16x16x32_f16(av[mfd], fp_frag[nf][pi], acc_o[mfd][nf], 0,0,0);
    }
    __builtin_amdgcn_s_setprio(0);
    __syncthreads();
  }
  #pragma unroll
  for (int nf=0;nf<2;nf++){
    float inv = 1.f/l_run[nf];
    size_t q = qbase + wave*32 + nf*16 + li;
    #pragma unroll
    for (int mfd=0;mfd<4;mfd++){
      int d0 = mfd*16 + g*4;
      f16x4 sa,sb;
      #pragma unroll
      for (int r=0;r<4;r++){
        _Float16 xa,xb; split2h(acc_o[mfd][nf][r]*inv, xa,xb);
        sa[r]=xa; sb[r]=xb;
      }
      size_t base = q*DMODEL + h*HDIM + d0;
      *(f16x4*)(o1+base)=sa; *(f16x4*)(o2+base)=sb;
    }
  }
}

// ---------------- fused: x2 = x + rmsnorm(ao)*g_post ; h = bf16(rmsnorm(x2)*g_pre) ;
//                  router logits/softmax/top-2 from the same fp32 registers ----------------
__global__ __launch_bounds__(256) void attnres_router_kernel(
    const float* __restrict__ x, const float* __restrict__ ao,
    const float* __restrict__ gpost, const float* __restrict__ gpre,
    const float* __restrict__ Wg,
    float* __restrict__ x2, short* __restrict__ h,
    float* __restrict__ probs_out, int* __restrict__ tok_list,
    float* __restrict__ w_list, int* __restrict__ counts)
{
  int row = blockIdx.x, tid = threadIdx.x;
  float4 a  = ((const float4*)(ao + (size_t)row*DMODEL))[tid];
  float4 xv = ((const float4*)(x  + (size_t)row*DMODEL))[tid];
  float ss = a.x*a.x + a.y*a.y + a.z*a.z + a.w*a.w;
  #pragma unroll
  for (int off=32; off; off>>=1) ss += __shfl_down(ss, off);
  __shared__ float red[4];
  if ((tid&63)==0) red[tid>>6] = ss;
  __syncthreads();
  float rs1 = rsqrtf((red[0]+red[1]+red[2]+red[3])*(1.f/1024.f) + EPSV);
  float4 gp = ((const float4*)gpost)[tid];
  float4 o;
  o.x = xv.x + a.x*rs1*gp.x; o.y = xv.y + a.y*rs1*gp.y;
  o.z = xv.z + a.z*rs1*gp.z; o.w = xv.w + a.w*rs1*gp.w;
  ((float4*)(x2 + (size_t)row*DMODEL))[tid] = o;
  float s2 = o.x*o.x + o.y*o.y + o.z*o.z + o.w*o.w;
  __syncthreads();
  #pragma unroll
  for (int off=32; off; off>>=1) s2 += __shfl_down(s2, off);
  if ((tid&63)==0) red[tid>>6] = s2;
  __syncthreads();
  float rs2 = rsqrtf((red[0]+red[1]+red[2]+red[3])*(1.f/1024.f) + EPSV);
  float4 gm = ((const float4*)gpre)[tid];
  float n0 = o.x*rs2*gm.x, n1 = o.y*rs2*gm.y, n2 = o.z*rs2*gm.z, n3 = o.w*rs2*gm.w;
  short4 hs;
  hs.x = f2b(n0); hs.y = f2b(n1); hs.z = f2b(n2); hs.w = f2b(n3);
  *(short4*)(h + (size_t)row*DMODEL + tid*4) = hs;
  // router partial logits (fp32): this thread owns dims tid*4..tid*4+3
  const float* wr = Wg + (size_t)(tid*4)*NE;
  float le[8];
  #pragma unroll
  for (int e=0;e<8;e++)
    le[e] = n0*wr[e] + n1*wr[NE+e] + n2*wr[2*NE+e] + n3*wr[3*NE+e];
  #pragma unroll
  for (int e=0;e<8;e++)
    #pragma unroll
    for (int off=32; off; off>>=1) le[e] += __shfl_xor(le[e], off);
  __shared__ float redl[4][8];
  if ((tid&63)==0)
    #pragma unroll
    for (int e=0;e<8;e++) redl[tid>>6][e] = le[e];
  __syncthreads();
  if (tid == 0){
    float l[8];
    #pragma unroll
    for (int e=0;e<8;e++) l[e] = redl[0][e]+redl[1][e]+redl[2][e]+redl[3][e];
    float mx = l[0];
    #pragma unroll
    for (int e=1;e<8;e++) mx = fmaxf(mx, l[e]);
    float pp[8], s = 0.f;
    #pragma unroll
    for (int e=0;e<8;e++){ pp[e] = expf(l[e]-mx); s += pp[e]; }
    float inv = 1.f/s;
    #pragma unroll
    for (int e=0;e<8;e++){ pp[e] *= inv; probs_out[(size_t)row*NE + e] = pp[e]; }
    int i1 = 0;
    #pragma unroll
    for (int e=1;e<8;e++) if (pp[e] > pp[i1]) i1 = e;
    int i2 = (i1==0) ? 1 : 0;
    #pragma unroll
    for (int e=0;e<8;e++) if (e != i1 && pp[e] > pp[i2]) i2 = e;
    int pos = atomicAdd(&counts[i1], 1);
    tok_list[i1*NTOK+pos] = row;              // slot 0
    w_list[i1*NTOK+pos] = pp[i1];
    pos = atomicAdd(&counts[i2], 1);
    tok_list[i2*NTOK+pos] = row | (1<<16);    // slot 1
    w_list[i2*NTOK+pos] = pp[i2];
  }
}

// ---------------- MoE grouped GEMM1: mid = gelu(h @ We1[e]^T) ----------------
// grid x = m-tiles (B-tile shared by consecutive blocks; A panel ~2MB L2-resident).
// bases computed inline from counts (prefix kernel removed).
__global__ __launch_bounds__(256) void moe_gemm1_kernel(
    const short* __restrict__ h, const short* __restrict__ we1t,
    const int* __restrict__ tok_list, const int* __restrict__ counts,
    short* __restrict__ mid)
{
  int e = blockIdx.z;
  int cnt = counts[e];
  int m0 = blockIdx.x*128, n0 = blockIdx.y*128;
  if (m0 >= cnt) return;
  int base = 0;
  for (int j=0;j<NE;j++){ int c = counts[j]; if (j<e) base += c; }
  const short* Bt = we1t + (size_t)e*HIDD*DMODEL;
  const int* tl = tok_list + e*NTOK;
  __shared__ short lsA[128*32];
  __shared__ short lsB[128*32];
  int tid = threadIdx.x, wave = tid>>6, lane = tid&63;
  int li = lane&15, g = lane>>4;
  int wm = (wave>>1)*64, wn = (wave&1)*64;
  int srow = wave*32 + (lane>>2), scol = (lane&3)*8;
  const short* gA[2]; const short* gB[2];
  #pragma unroll
  for (int i=0;i<2;i++){
    int rr = min(m0+srow+i*16, cnt-1);
    gA[i] = h + (size_t)(tl[rr] & 0xFFFF)*DMODEL + scol;
    gB[i] = Bt + (size_t)(n0+srow+i*16)*DMODEL + scol;
  }
  f32x4 acc[4][4] = {};
  for (int k0=0; k0<DMODEL; k0+=32){
    #pragma unroll
    for (int i=0;i<2;i++){
      gl_lds16(gA[i]+k0, &lsA[(wave*32+i*16)*32]);
      gl_lds16(gB[i]+k0, &lsB[(wave*32+i*16)*32]);
    }
    __syncthreads();
    bf16x8 af[4], bfr[4];
    #pragma unroll
    for (int m=0;m<4;m++) af[m] = *(bf16x8*)&lsA[(wm+m*16+li)*32 + g*8];
    #pragma unroll
    for (int n=0;n<4;n++) bfr[n] = *(bf16x8*)&lsB[(wn+n*16+li)*32 + g*8];
    #pragma unroll
    for (int m=0;m<4;m++)
      #pragma unroll
      for (int n=0;n<4;n++)
        acc[m][n] = __builtin_amdgcn_mfma_f32_16x16x32_bf16(af[m], bfr[n], acc[m][n], 0,0,0);
    __syncthreads();
  }
  #pragma unroll
  for (int m=0;m<4;m++){
    int lr0 = wm + m*16 + (g<<2);
    #pragma unroll
    for (int n=0;n<4;n++){
      int col = n0 + wn + n*16 + li;
      #pragma unroll
      for (int r=0;r<4;r++){
        int gr = m0 + lr0 + r;
        if (gr < cnt){
          float tval = acc[m][n][r];
          float u = 1.5957691216057308f*(tval + 0.044715f*tval*tval*tval);
          float ge = tval / (1.f + __expf(-u));
          mid[(size_t)(base+gr)*HIDD + col] = f2b(ge);
        }
      }
    }
  }
}

// ---------------- MoE grouped GEMM2: eo[slot][tok] = w*(mid @ We2[e]^T) ----------------
__global__ __launch_bounds__(256) void moe_gemm2_kernel(
    const short* __restrict__ mid, const short* __restrict__ we2t,
    const int* __restrict__ tok_list, const float* __restrict__ w_list,
    const int* __restrict__ counts, float* __restrict__ eo)
{
  int e = blockIdx.z;
  int cnt = counts[e];
  int m0 = blockIdx.x*128, n0 = blockIdx.y*128;
  if (m0 >= cnt) return;
  int base = 0;
  for (int j=0;j<NE;j++){ int c = counts[j]; if (j<e) base += c; }
  const short* A  = mid + (size_t)base*HIDD;
  const short* Bt = we2t + (size_t)e*DMODEL*HIDD;
  const int* tl = tok_list + e*NTOK;
  const float* wl = w_list + e*NTOK;
  __shared__ short lsA[128*32];
  __shared__ short lsB[128*32];
  int tid = threadIdx.x, wave = tid>>6, lane = tid&63;
  int li = lane&15, g = lane>>4;
  int wm = (wave>>1)*64, wn = (wave&1)*64;
  int srow = wave*32 + (lane>>2), scol = (lane&3)*8;
  const short* gA[2]; const short* gB[2];
  #pragma unroll
  for (int i=0;i<2;i++){
    int rr = min(m0+srow+i*16, cnt-1);
    gA[i] = A + (size_t)rr*HIDD + scol;
    gB[i] = Bt + (size_t)(n0+srow+i*16)*HIDD + scol;
  }
  f32x4 acc[4][4] = {};
  for (int k0=0; k0<HIDD; k0+=32){
    #pragma unroll
    for (int i=0;i<2;i++){
      gl_lds16(gA[i]+k0, &lsA[(wave*32+i*16)*32]);
      gl_lds16(gB[i]+k0, &lsB[(wave*32+i*16)*32]);
    }
    __syncthreads();
    bf16x8 af[4], bfr[4];
    #pragma unroll
    for (int m=0;m<4;m++) af[m] = *(bf16x8*)&lsA[(wm+m*16+li)*32 + g*8];
    #pragma unroll
    for (int n=0;n<4;n++) bfr[n] = *(bf16x8*)&lsB[(wn+n*16+li)*32 + g*8];
    #pragma unroll
    for (int m=0;m<4;m++)
      #pragma unroll
      for (int n=0;n<4;n++)
        acc[m][n] = __builtin_amdgcn_mfma_f32_16x16x32_bf16(af[m], bfr[n], acc[m][n], 0,0,0);
    __syncthreads();
  }
  #pragma unroll
  for (int m=0;m<4;m++){
    int lr0 = wm + m*16 + (g<<2);
    #pragma unroll
    for (int n=0;n<4;n++){
      int col = n0 + wn + n*16 + li;
      #pragma unroll
      for (int r=0;r<4;r++){
        int gr = m0 + lr0 + r;
        if (gr < cnt){
          int pv = tl[gr];
          eo[((size_t)(pv>>16)*NTOK + (pv & 0xFFFF))*DMODEL + col] = wl[gr]*acc[m][n][r];
        }
      }
    }
  }
}

// ---------------- out = x2 + rmsnorm(eo0+eo1)*g_post_moe ----------------
__global__ __launch_bounds__(256) void final_kernel(
    const float* __restrict__ x2, const float* __restrict__ eo,
    const float* __restrict__ g, float* __restrict__ out)
{
  int row = blockIdx.x, tid = threadIdx.x;
  float4 m0 = ((const float4*)(eo + (size_t)row*DMODEL))[tid];
  float4 m1 = ((const float4*)(eo + (size_t)(NTOK+row)*DMODEL))[tid];
  float4 mv;
  mv.x = m0.x+m1.x; mv.y = m0.y+m1.y; mv.z = m0.z+m1.z; mv.w = m0.w+m1.w;
  float4 xv = ((const float4*)(x2  + (size_t)row*DMODEL))[tid];
  float ss = mv.x*mv.x + mv.y*mv.y + mv.z*mv.z + mv.w*mv.w;
  #pragma unroll
  for (int off=32; off; off>>=1) ss += __shfl_down(ss, off);
  __shared__ float red[4];
  if ((tid&63)==0) red[tid>>6] = ss;
  __syncthreads();
  float rs = rsqrtf((red[0]+red[1]+red[2]+red[3])*(1.f/1024.f) + EPSV);
  float4 gv = ((const float4*)g)[tid];
  float4 o;
  o.x = xv.x + mv.x*rs*gv.x; o.y = xv.y + mv.y*rs*gv.y;
  o.z = xv.z + mv.z*rs*gv.z; o.w = xv.w + mv.w*rs*gv.w;
  ((float4*)(out + (size_t)row*DMODEL))[tid] = o;
}

extern "C" void kernel_launch(void* const* d_in, const int* in_sizes, int n_in,
                              void* d_out, int out_size, void* d_ws, size_t ws_size,
                              hipStream_t stream) {
  (void)in_sizes; (void)n_in; (void)out_size; (void)ws_size;
  const float* x          = (const float*)d_in[0];
  const float* g_pre_mqa  = (const float*)d_in[1];
  const float* g_post_mqa = (const float*)d_in[2];
  const float* g_pre_moe  = (const float*)d_in[3];
  const float* g_post_moe = (const float*)d_in[4];
  const float* Wq         = (const float*)d_in[5];
  const float* Wk         = (const float*)d_in[6];
  const float* Wv         = (const float*)d_in[7];
  const float* Wo         = (const float*)d_in[8];
  const float* Wg         = (const float*)d_in[9];
  const float* We1        = (const float*)d_in[10];
  const float* We2        = (const float*)d_in[11];

  float* out_x = (float*)d_out;
  float* out_probs = out_x + (size_t)NTOK*DMODEL;

  char* p = (char*)d_ws;
  size_t off = 0;
  auto alloc = [&](size_t bytes)->char*{
    char* r = p + off; off = (off + bytes + 255) & ~(size_t)255; return r; };

  short* we1t = (short*)alloc((size_t)NE*HIDD*DMODEL*2);       // 64M
  short* we2t = (short*)alloc((size_t)NE*DMODEL*HIDD*2);       // 64M
  short* mid  = (short*)alloc((size_t)2*NTOK*HIDD*2);          // 64M

  // region A: xn1 fp16 planes (2x8.4M), later ao fp32 (16.8M)
  char* regA = alloc((size_t)2*NTOK*DMODEL*2);
  _Float16* xn1p1 = (_Float16*)regA;
  _Float16* xn1p2 = (_Float16*)(regA + (size_t)NTOK*DMODEL*2);
  float* ao       = (float*)regA;

  _Float16* wqkvT1 = (_Float16*)alloc((size_t)QKVW*DMODEL*2);
  _Float16* wqkvT2 = (_Float16*)alloc((size_t)QKVW*DMODEL*2);
  _Float16* woT1   = (_Float16*)alloc((size_t)DMODEL*DMODEL*2);
  _Float16* woT2   = (_Float16*)alloc((size_t)DMODEL*DMODEL*2);

  // region B: attn fp16 planes (2x8.4M)
  char* regB = alloc((size_t)2*NTOK*DMODEL*2);
  _Float16* attnp1 = (_Float16*)regB;
  _Float16* attnp2 = (_Float16*)(regB + (size_t)NTOK*DMODEL*2);

  // region C: qkvf fp16 planes (2x9.4M=18.9M), later eo fp32 2 slabs (33.6M) + hbuf (8.4M)
  char* regC = alloc((size_t)2*NTOK*DMODEL*4 + (size_t)NTOK*DMODEL*2);
  _Float16* qkvf1 = (_Float16*)regC;
  _Float16* qkvf2 = (_Float16*)(regC + (size_t)NTOK*QKVW*2);
  float* eo    = (float*)regC;
  short* hbuf  = (short*)(regC + (size_t)2*NTOK*DMODEL*4);

  _Float16* vt1 = (_Float16*)alloc((size_t)2*HDIM*SEQL*2);
  _Float16* vt2 = (_Float16*)alloc((size_t)2*HDIM*SEQL*2);
  float* x2  = (float*)alloc((size_t)NTOK*DMODEL*4);
  int*   tok_l  = (int*)  alloc((size_t)NE*NTOK*4);
  float* w_l    = (float*)alloc((size_t)NE*NTOK*4);
  int*   counts = (int*)  alloc(256);

  // ---- weights prep ----
  transpose_conv_kernel<<<dim3(HIDD/32, DMODEL/32, NE), 256, 0, stream>>>(
      We1, we1t, DMODEL, HIDD, (long)DMODEL*HIDD, (long)HIDD*DMODEL);
  transpose_conv_kernel<<<dim3(DMODEL/32, HIDD/32, NE), 256, 0, stream>>>(
      We2, we2t, HIDD, DMODEL, (long)HIDD*DMODEL, (long)DMODEL*HIDD);
  transpose_split2f16_kernel<<<dim3(DMODEL/32, DMODEL/32), 256, 0, stream>>>(
      Wq, wqkvT1, wqkvT2, DMODEL, DMODEL, 0, DMODEL);
  transpose_split2f16_kernel<<<dim3(HDIM/32, DMODEL/32), 256, 0, stream>>>(
      Wk, wqkvT1, wqkvT2, DMODEL, HDIM, DMODEL, DMODEL);
  transpose_split2f16_kernel<<<dim3(HDIM/32, DMODEL/32), 256, 0, stream>>>(
      Wv, wqkvT1, wqkvT2, DMODEL, HDIM, DMODEL+HDIM, DMODEL);
  transpose_split2f16_kernel<<<dim3(DMODEL/32, DMODEL/32), 256, 0, stream>>>(
      Wo, woT1, woT2, DMODEL, DMODEL, 0, DMODEL);

  // ---- pre-router chain: fp16x2 GEMMs (x = m-tiles) + fp16 attention ----
  rms_split2_kernel<<<NTOK, 256, 0, stream>>>(x, g_pre_mqa, xn1p1, xn1p2);
  gemm_f16x2s_kernel<<<dim3(NTOK/128, QKVW/128), 256, 0, stream>>>(
      xn1p1, xn1p2, wqkvT1, wqkvT2, qkvf1, qkvf2, DMODEL, QKVW, OUTSCL*ASCL);
  vtrans_split2_kernel<<<dim3(SEQL/32, HDIM/32, 2), 256, 0, stream>>>(qkvf1, qkvf2, vt1, vt2);
  attn_f16_kernel<<<dim3(SEQL/128, NH, 2), 256, 0, stream>>>(
      qkvf1, qkvf2, vt1, vt2, attnp1, attnp2);
  gemm_f16x2_kernel<<<dim3(NTOK/128, DMODEL/128), 256, 0, stream>>>(
      attnp1, attnp2, woT1, woT2, ao, DMODEL, DMODEL, OUTSCL);

  // ---- fused residual+rmsnorm+router, then grouped MoE (x = m-tiles) ----
  hipMemsetAsync(counts, 0, 32, stream);
  attnres_router_kernel<<<NTOK, 256, 0, stream>>>(
      x, ao, g_post_mqa, g_pre_moe, Wg, x2, hbuf, out_probs, tok_l, w_l, counts);
  moe_gemm1_kernel<<<dim3(NTOK/128, HIDD/128, NE), 256, 0, stream>>>(
      hbuf, we1t, tok_l, counts, mid);
  moe_gemm2_kernel<<<dim3(NTOK/128, DMODEL/128, NE), 256, 0, stream>>>(
      mid, we2t, tok_l, w_l, counts, eo);
  final_kernel<<<NTOK, 256, 0, stream>>>(x2, eo, g_post_moe, out_x);
}

// Round 11
// 726.942 us; speedup vs baseline: 1.5832x; 1.5832x over previous
//
#include <hip/hip_runtime.h>
#include <hip/hip_bf16.h>
#include <math.h>

#define NTOK   4096
#define DMODEL 1024
#define SEQL   2048
#define QKVW   1152     // 1024 q + 64 k + 64 v
#define NH     16
#define HDIM   64
#define NE     8
#define HIDD   4096
#define EPSV   1e-5f
#define KT     32       // attention kv-tile

// fp16 scales: activations *2^8, weights *2^12; folded out via OUTSCL.
// P scaled 2^15 via PBIAS; defer-max THR=0.5 keeps p_bar <= 2^15*e^0.5 = 54k < 65504.
#define ASCL   256.f
#define WSCL   4096.f
#define OUTSCL (1.f/1048576.f)          // 2^-20
#define SSCALE (0.125f/65536.f)         // 1/sqrt(64) * 2^-16 (Q,K both *2^8)
#define PBIAS  10.397207708399179f      // 15*ln2 -> P scaled 2^15
#define DTHR   0.5f                     // defer-max threshold (fp16-P overflow-safe)

typedef __attribute__((ext_vector_type(8))) short bf16x8;
typedef __attribute__((ext_vector_type(8))) _Float16 f16x8;
typedef __attribute__((ext_vector_type(4))) _Float16 f16x4;
typedef __attribute__((ext_vector_type(4))) float f32x4;

#define GLOBAL_AS __attribute__((address_space(1)))
#define LDS_AS    __attribute__((address_space(3)))
__device__ __forceinline__ void gl_lds16(const void* g, void* l){
  __builtin_amdgcn_global_load_lds((const GLOBAL_AS void*)g, (LDS_AS void*)l, 16u, 0, 0u);
}

__device__ __forceinline__ short f2b(float x){
  __hip_bfloat16 h = __float2bfloat16(x);
  return *reinterpret_cast<short*>(&h);
}
__device__ __forceinline__ void split2h(float x, _Float16& a, _Float16& b){
  a = (_Float16)x;
  b = (_Float16)(x - (float)a);
}

// ---------------- transpose fp32 [R][C] -> bf16 [C][R] (expert weights), short4 stores ----------------
__global__ __launch_bounds__(256) void transpose_conv_kernel(
    const float* __restrict__ in, short* __restrict__ out,
    int R, int C, long inb, long outb)
{
  __shared__ float tile[32][33];
  in  += (size_t)blockIdx.z * inb;
  out += (size_t)blockIdx.z * outb;
  int c0 = blockIdx.x*32, r0 = blockIdx.y*32;
  int tx = threadIdx.x & 31, ty = threadIdx.x >> 5;
  #pragma unroll
  for (int i=0;i<4;i++)
    tile[ty+i*8][tx] = in[(size_t)(r0+ty+i*8)*C + c0+tx];   // tile[r][c]
  __syncthreads();
  int cl = threadIdx.x >> 3, quad = threadIdx.x & 7;
  short4 s;
  s.x = f2b(tile[quad*4+0][cl]);
  s.y = f2b(tile[quad*4+1][cl]);
  s.z = f2b(tile[quad*4+2][cl]);
  s.w = f2b(tile[quad*4+3][cl]);
  *(short4*)&out[(size_t)(c0+cl)*R + r0 + quad*4] = s;
}

// ---------------- transpose fp32 [R][C] -> 2 fp16 planes [C+rowOff][outLD=R], *2^12 ----------------
__global__ __launch_bounds__(256) void transpose_split2f16_kernel(
    const float* __restrict__ in, _Float16* __restrict__ o1, _Float16* __restrict__ o2,
    int R, int C, int rowOff, int outLD)
{
  __shared__ float tile[32][33];
  int c0 = blockIdx.x*32, r0 = blockIdx.y*32;
  int tx = threadIdx.x & 31, ty = threadIdx.x >> 5;
  #pragma unroll
  for (int i=0;i<4;i++)
    tile[ty+i*8][tx] = in[(size_t)(r0+ty+i*8)*C + c0+tx];
  __syncthreads();
  #pragma unroll
  for (int i=0;i<4;i++){
    float v = tile[tx][ty+i*8] * WSCL;
    _Float16 va,vb; split2h(v,va,vb);
    size_t idx = (size_t)(c0+ty+i*8+rowOff)*outLD + r0+tx;
    o1[idx]=va; o2[idx]=vb;
  }
}

// ---------------- rmsnorm(x)*g*2^8 -> 2 fp16 planes ----------------
__global__ __launch_bounds__(256) void rms_split2_kernel(
    const float* __restrict__ x, const float* __restrict__ g,
    _Float16* __restrict__ o1, _Float16* __restrict__ o2)
{
  int row = blockIdx.x, tid = threadIdx.x;
  const float4* xr = (const float4*)(x + (size_t)row*DMODEL);
  float4 v = xr[tid];
  float ss = v.x*v.x + v.y*v.y + v.z*v.z + v.w*v.w;
  #pragma unroll
  for (int off=32; off; off>>=1) ss += __shfl_down(ss, off);
  __shared__ float red[4];
  if ((tid&63)==0) red[tid>>6] = ss;
  __syncthreads();
  float rs = rsqrtf((red[0]+red[1]+red[2]+red[3])*(1.f/1024.f) + EPSV) * ASCL;
  float4 gv = ((const float4*)g)[tid];
  float o[4] = {v.x*rs*gv.x, v.y*rs*gv.y, v.z*rs*gv.z, v.w*rs*gv.w};
  f16x4 s1,s2;
  #pragma unroll
  for (int c=0;c<4;c++){ _Float16 a,b; split2h(o[c],a,b); s1[c]=a; s2[c]=b; }
  size_t base = (size_t)row*DMODEL + tid*4;
  *(f16x4*)(o1+base) = s1; *(f16x4*)(o2+base) = s2;
}

// ---------------- V^T build from qkv fp16 planes -> vt fp16 planes [2][64][2048] ----------------
// planes already carry *2^8; no rescale. (r3 postmortem: never shadow the batch index.)
__global__ __launch_bounds__(256) void vtrans_split2_kernel(
    const _Float16* __restrict__ p1, const _Float16* __restrict__ p2,
    _Float16* __restrict__ o1, _Float16* __restrict__ o2)
{
  __shared__ float tile[32][33];
  int s0 = blockIdx.x*32, d0 = blockIdx.y*32, bb = blockIdx.z;
  int tx = threadIdx.x & 31, ty = threadIdx.x >> 5;
  #pragma unroll
  for (int i=0;i<4;i++){
    size_t idx = (size_t)(bb*SEQL + s0+ty+i*8)*QKVW + DMODEL+HDIM + d0+tx;
    tile[ty+i*8][tx] = (float)p1[idx] + (float)p2[idx];
  }
  __syncthreads();
  #pragma unroll
  for (int i=0;i<4;i++){
    float v = tile[tx][ty+i*8];          // [s=tx][d=ty+i*8], already *2^8
    _Float16 va,vb; split2h(v,va,vb);
    size_t idx = (size_t)(bb*HDIM + d0+ty+i*8)*SEQL + s0+tx;
    o1[idx]=va; o2[idx]=vb;
  }
}

// ---------------- fp32-accurate GEMM via 3-pass fp16x2 MFMA + global_load_lds ----------------
// grid: x = n-tiles, y = m-tiles (ROUND-9 PROVEN; r10's m-fastest thrashed L2 -> reverted)
__global__ __launch_bounds__(256) void gemm_f16x2_kernel(
    const _Float16* __restrict__ a1, const _Float16* __restrict__ a2,
    const _Float16* __restrict__ b1, const _Float16* __restrict__ b2,
    float* __restrict__ C, int K, int ldc, float outscale)
{
  __shared__ _Float16 lsA[2][128*32];
  __shared__ _Float16 lsB[2][128*32];
  int m0 = blockIdx.y*128, n0 = blockIdx.x*128;
  int tid = threadIdx.x, wave = tid>>6, lane = tid&63;
  int g = lane>>4, li = lane&15;
  int wm = (wave>>1)*64, wn = (wave&1)*64;
  const _Float16* Ap[2] = {a1,a2};
  const _Float16* Bp[2] = {b1,b2};
  int srow = wave*32 + (lane>>2), scol = (lane&3)*8;
  const _Float16* gA[2][2]; const _Float16* gB[2][2];
  #pragma unroll
  for (int p=0;p<2;p++)
    #pragma unroll
    for (int i=0;i<2;i++){
      gA[p][i] = Ap[p] + (size_t)(m0+srow+i*16)*K + scol;
      gB[p][i] = Bp[p] + (size_t)(n0+srow+i*16)*K + scol;
    }
  f32x4 acc[4][4] = {};
  for (int k0=0; k0<K; k0+=32){
    #pragma unroll
    for (int p=0;p<2;p++)
      #pragma unroll
      for (int i=0;i<2;i++){
        gl_lds16(gA[p][i]+k0, &lsA[p][(wave*32+i*16)*32]);
        gl_lds16(gB[p][i]+k0, &lsB[p][(wave*32+i*16)*32]);
      }
    __syncthreads();
    #pragma unroll
    for (int i=0;i<2;i++){
      f16x8 af[4];
      #pragma unroll
      for (int m=0;m<4;m++) af[m] = *(f16x8*)&lsA[i][(wm+m*16+li)*32 + g*8];
      #pragma unroll
      for (int j=0;j<2-i;j++){
        #pragma unroll
        for (int n=0;n<4;n++){
          f16x8 bfr = *(f16x8*)&lsB[j][(wn+n*16+li)*32 + g*8];
          #pragma unroll
          for (int m=0;m<4;m++)
            acc[m][n] = __builtin_amdgcn_mfma_f32_16x16x32_f16(af[m], bfr, acc[m][n], 0,0,0);
        }
      }
    }
    __syncthreads();
  }
  #pragma unroll
  for (int m=0;m<4;m++){
    int lr0 = wm + m*16 + g*4;
    #pragma unroll
    for (int n=0;n<4;n++){
      int col = n0 + wn + n*16 + li;
      #pragma unroll
      for (int r=0;r<4;r++)
        C[(size_t)(m0+lr0+r)*ldc + col] = acc[m][n][r]*outscale;
    }
  }
}

// ---------------- same GEMM, split-epilogue: writes 2 fp16 planes (for QKV) ----------------
__global__ __launch_bounds__(256) void gemm_f16x2s_kernel(
    const _Float16* __restrict__ a1, const _Float16* __restrict__ a2,
    const _Float16* __restrict__ b1, const _Float16* __restrict__ b2,
    _Float16* __restrict__ o1, _Float16* __restrict__ o2, int K, int ldc, float outscale)
{
  __shared__ _Float16 lsA[2][128*32];
  __shared__ _Float16 lsB[2][128*32];
  int m0 = blockIdx.y*128, n0 = blockIdx.x*128;
  int tid = threadIdx.x, wave = tid>>6, lane = tid&63;
  int g = lane>>4, li = lane&15;
  int wm = (wave>>1)*64, wn = (wave&1)*64;
  const _Float16* Ap[2] = {a1,a2};
  const _Float16* Bp[2] = {b1,b2};
  int srow = wave*32 + (lane>>2), scol = (lane&3)*8;
  const _Float16* gA[2][2]; const _Float16* gB[2][2];
  #pragma unroll
  for (int p=0;p<2;p++)
    #pragma unroll
    for (int i=0;i<2;i++){
      gA[p][i] = Ap[p] + (size_t)(m0+srow+i*16)*K + scol;
      gB[p][i] = Bp[p] + (size_t)(n0+srow+i*16)*K + scol;
    }
  f32x4 acc[4][4] = {};
  for (int k0=0; k0<K; k0+=32){
    #pragma unroll
    for (int p=0;p<2;p++)
      #pragma unroll
      for (int i=0;i<2;i++){
        gl_lds16(gA[p][i]+k0, &lsA[p][(wave*32+i*16)*32]);
        gl_lds16(gB[p][i]+k0, &lsB[p][(wave*32+i*16)*32]);
      }
    __syncthreads();
    #pragma unroll
    for (int i=0;i<2;i++){
      f16x8 af[4];
      #pragma unroll
      for (int m=0;m<4;m++) af[m] = *(f16x8*)&lsA[i][(wm+m*16+li)*32 + g*8];
      #pragma unroll
      for (int j=0;j<2-i;j++){
        #pragma unroll
        for (int n=0;n<4;n++){
          f16x8 bfr = *(f16x8*)&lsB[j][(wn+n*16+li)*32 + g*8];
          #pragma unroll
          for (int m=0;m<4;m++)
            acc[m][n] = __builtin_amdgcn_mfma_f32_16x16x32_f16(af[m], bfr, acc[m][n], 0,0,0);
        }
      }
    }
    __syncthreads();
  }
  #pragma unroll
  for (int m=0;m<4;m++){
    int lr0 = wm + m*16 + g*4;
    #pragma unroll
    for (int n=0;n<4;n++){
      int col = n0 + wn + n*16 + li;
      #pragma unroll
      for (int r=0;r<4;r++){
        float val = acc[m][n][r]*outscale;
        _Float16 xa,xb; split2h(val,xa,xb);
        size_t idx = (size_t)(m0+lr0+r)*ldc + col;
        o1[idx]=xa; o2[idx]=xb;
      }
    }
  }
}

// ---------------- flash attention: fp16x2 QK^T + fp16x2 PV, T14 async-stage, setprio ----------------
__global__ __launch_bounds__(256) void attn_f16_kernel(
    const _Float16* __restrict__ q1, const _Float16* __restrict__ q2,
    const _Float16* __restrict__ v1, const _Float16* __restrict__ v2,
    _Float16* __restrict__ o1, _Float16* __restrict__ o2)
{
  __shared__ _Float16 Ks[32*136];  // [kv][plane*64+d]
  __shared__ _Float16 Vs[64*72];   // [d][plane*32+kv]
  int qt = blockIdx.x, h = blockIdx.y, b = blockIdx.z;
  int tid = threadIdx.x, wave = tid>>6, lane = tid&63;
  int g = lane>>4, li = lane&15;
  size_t qbase = (size_t)b*SEQL + qt*128;
  const _Float16* qsrc[2] = {q1,q2};
  const _Float16* vsrc[2] = {v1,v2};
  f16x8 qf[2][2][2];
  #pragma unroll
  for (int nf=0;nf<2;nf++){
    size_t qrow = qbase + wave*32 + nf*16 + li;
    #pragma unroll
    for (int j=0;j<2;j++)
      #pragma unroll
      for (int kk=0;kk<2;kk++)
        qf[nf][j][kk] = *(const f16x8*)(qsrc[j] + qrow*QKVW + h*HDIM + kk*32 + g*8);
  }
  const _Float16* kga[2]; int klds[2];
  const _Float16* vga[2]; int vlds[2];
  #pragma unroll
  for (int i=0;i<2;i++){
    int c = tid + 256*i;
    { int row=c>>4, sub=c&15, pl=sub>>3, d=(sub&7)*8;
      kga[i] = qsrc[pl] + ((size_t)b*SEQL + row)*QKVW + DMODEL + d;
      klds[i] = row*136 + pl*64 + d; }
    { int row=c>>3, sub=c&7, pl=sub>>2, s8=(sub&3)*8;
      vga[i] = vsrc[pl] + ((size_t)b*HDIM + row)*SEQL + s8;
      vlds[i] = row*72 + pl*32 + s8; }
  }
  f16x8 kreg[2], vreg[2];
  #pragma unroll
  for (int i=0;i<2;i++){ kreg[i]=*(const f16x8*)kga[i]; vreg[i]=*(const f16x8*)vga[i]; }

  float m_run[2] = {-1e30f,-1e30f}, l_run[2] = {0.f,0.f};
  f32x4 acc_o[4][2] = {};
  int src1 = (((2*g)&3)<<4) + li;
  int src2 = (((2*g+1)&3)<<4) + li;
  bool hi_half = (g>=2);

  for (int kvt=0; kvt<SEQL/KT; kvt++){
    #pragma unroll
    for (int i=0;i<2;i++){
      *(f16x8*)&Ks[klds[i]] = kreg[i];
      *(f16x8*)&Vs[vlds[i]] = vreg[i];
    }
    __syncthreads();
    if (kvt+1 < SEQL/KT){
      #pragma unroll
      for (int i=0;i<2;i++){
        kreg[i] = *(const f16x8*)(kga[i] + (size_t)(kvt+1)*KT*QKVW);
        vreg[i] = *(const f16x8*)(vga[i] + (size_t)(kvt+1)*KT);
      }
    }
    f32x4 s_acc[2][2] = {};
    __builtin_amdgcn_s_setprio(1);
    #pragma unroll
    for (int i=0;i<2;i++){
      #pragma unroll
      for (int kk=0;kk<2;kk++){
        f16x8 af[2];
        #pragma unroll
        for (int mf=0;mf<2;mf++)
          af[mf] = *(f16x8*)&Ks[(mf*16+li)*136 + i*64 + kk*32 + g*8];
        #pragma unroll
        for (int j=0;j<2-i;j++){
          #pragma unroll
          for (int nf=0;nf<2;nf++){
            #pragma unroll
            for (int mf=0;mf<2;mf++)
              s_acc[mf][nf] = __builtin_amdgcn_mfma_f32_16x16x32_f16(af[mf], qf[nf][j][kk], s_acc[mf][nf], 0,0,0);
          }
        }
      }
    }
    __builtin_amdgcn_s_setprio(0);
    float p[2][2][4];
    #pragma unroll
    for (int nf=0;nf<2;nf++){
      float mx = -1e30f;
      #pragma unroll
      for (int mf=0;mf<2;mf++)
        #pragma unroll
        for (int r=0;r<4;r++) mx = fmaxf(mx, s_acc[mf][nf][r]);
      mx = fmaxf(mx, __shfl_xor(mx,16));
      mx = fmaxf(mx, __shfl_xor(mx,32));
      mx *= SSCALE;
      if (!__all(mx <= m_run[nf] + DTHR)){
        float mn = fmaxf(m_run[nf], mx);
        float al = __expf(m_run[nf] - mn);
        m_run[nf] = mn;
        l_run[nf] *= al;
        #pragma unroll
        for (int mfd=0; mfd<4; mfd++){
          acc_o[mfd][nf][0]*=al; acc_o[mfd][nf][1]*=al;
          acc_o[mfd][nf][2]*=al; acc_o[mfd][nf][3]*=al;
        }
      }
      float rsum = 0.f;
      #pragma unroll
      for (int mf=0;mf<2;mf++)
        #pragma unroll
        for (int r=0;r<4;r++){
          float pv = __expf(s_acc[mf][nf][r]*SSCALE - m_run[nf] + PBIAS);
          p[mf][nf][r] = pv; rsum += pv;
        }
      rsum += __shfl_xor(rsum,16);
      rsum += __shfl_xor(rsum,32);
      l_run[nf] += rsum;
    }
    f16x8 fp_frag[2][2];
    #pragma unroll
    for (int nf=0;nf<2;nf++){
      float p8[8];
      #pragma unroll
      for (int jj=0;jj<4;jj++){
        float v0 = __shfl(p[0][nf][jj], src1);
        float vv1 = __shfl(p[1][nf][jj], src1);
        p8[jj] = hi_half ? vv1 : v0;
        float w0 = __shfl(p[0][nf][jj], src2);
        float w1 = __shfl(p[1][nf][jj], src2);
        p8[4+jj] = hi_half ? w1 : w0;
      }
      #pragma unroll
      for (int jj=0;jj<8;jj++){
        _Float16 xa,xb; split2h(p8[jj], xa,xb);
        fp_frag[nf][0][jj]=xa; fp_frag[nf][1][jj]=xb;
      }
    }
    __builtin_amdgcn_s_setprio(1);
    #pragma unroll
    for (int vj=0;vj<2;vj++){
      f16x8 av[4];
      #pragma unroll
      for (int mfd=0;mfd<4;mfd++)
        av[mfd] = *(f16x8*)&Vs[(mfd*16+li)*72 + vj*32 + g*8];
      #pragma unroll
      for (int pi=0; pi<2-vj; pi++)
        #pragma unroll
        for (int mfd=0;mfd<4;mfd++)
          #pragma unroll
          for (int nf=0;nf<2;nf++)
            acc_o[mfd][nf] = __builtin_amdgcn_mfma_f32_16x16x32_f16(av[mfd], fp_frag[nf][pi], acc_o[mfd][nf], 0,0,0);
    }
    __builtin_amdgcn_s_setprio(0);
    __syncthreads();
  }
  #pragma unroll
  for (int nf=0;nf<2;nf++){
    float inv = 1.f/l_run[nf];
    size_t q = qbase + wave*32 + nf*16 + li;
    #pragma unroll
    for (int mfd=0;mfd<4;mfd++){
      int d0 = mfd*16 + g*4;
      f16x4 sa,sb;
      #pragma unroll
      for (int r=0;r<4;r++){
        _Float16 xa,xb; split2h(acc_o[mfd][nf][r]*inv, xa,xb);
        sa[r]=xa; sb[r]=xb;
      }
      size_t base = q*DMODEL + h*HDIM + d0;
      *(f16x4*)(o1+base)=sa; *(f16x4*)(o2+base)=sb;
    }
  }
}

// ---------------- fused: x2 = x + rmsnorm(ao)*g_post ; h = bf16(rmsnorm(x2)*g_pre) ;
//                  router logits/softmax/top-2 from the same fp32 registers ----------------
__global__ __launch_bounds__(256) void attnres_router_kernel(
    const float* __restrict__ x, const float* __restrict__ ao,
    const float* __restrict__ gpost, const float* __restrict__ gpre,
    const float* __restrict__ Wg,
    float* __restrict__ x2, short* __restrict__ h,
    float* __restrict__ probs_out, int* __restrict__ tok_list,
    float* __restrict__ w_list, int* __restrict__ counts)
{
  int row = blockIdx.x, tid = threadIdx.x;
  float4 a  = ((const float4*)(ao + (size_t)row*DMODEL))[tid];
  float4 xv = ((const float4*)(x  + (size_t)row*DMODEL))[tid];
  float ss = a.x*a.x + a.y*a.y + a.z*a.z + a.w*a.w;
  #pragma unroll
  for (int off=32; off; off>>=1) ss += __shfl_down(ss, off);
  __shared__ float red[4];
  if ((tid&63)==0) red[tid>>6] = ss;
  __syncthreads();
  float rs1 = rsqrtf((red[0]+red[1]+red[2]+red[3])*(1.f/1024.f) + EPSV);
  float4 gp = ((const float4*)gpost)[tid];
  float4 o;
  o.x = xv.x + a.x*rs1*gp.x; o.y = xv.y + a.y*rs1*gp.y;
  o.z = xv.z + a.z*rs1*gp.z; o.w = xv.w + a.w*rs1*gp.w;
  ((float4*)(x2 + (size_t)row*DMODEL))[tid] = o;
  float s2 = o.x*o.x + o.y*o.y + o.z*o.z + o.w*o.w;
  __syncthreads();
  #pragma unroll
  for (int off=32; off; off>>=1) s2 += __shfl_down(s2, off);
  if ((tid&63)==0) red[tid>>6] = s2;
  __syncthreads();
  float rs2 = rsqrtf((red[0]+red[1]+red[2]+red[3])*(1.f/1024.f) + EPSV);
  float4 gm = ((const float4*)gpre)[tid];
  float n0 = o.x*rs2*gm.x, n1 = o.y*rs2*gm.y, n2 = o.z*rs2*gm.z, n3 = o.w*rs2*gm.w;
  short4 hs;
  hs.x = f2b(n0); hs.y = f2b(n1); hs.z = f2b(n2); hs.w = f2b(n3);
  *(short4*)(h + (size_t)row*DMODEL + tid*4) = hs;
  // router partial logits (fp32): this thread owns dims tid*4..tid*4+3
  const float* wr = Wg + (size_t)(tid*4)*NE;
  float le[8];
  #pragma unroll
  for (int e=0;e<8;e++)
    le[e] = n0*wr[e] + n1*wr[NE+e] + n2*wr[2*NE+e] + n3*wr[3*NE+e];
  #pragma unroll
  for (int e=0;e<8;e++)
    #pragma unroll
    for (int off=32; off; off>>=1) le[e] += __shfl_xor(le[e], off);
  __shared__ float redl[4][8];
  if ((tid&63)==0)
    #pragma unroll
    for (int e=0;e<8;e++) redl[tid>>6][e] = le[e];
  __syncthreads();
  if (tid == 0){
    float l[8];
    #pragma unroll
    for (int e=0;e<8;e++) l[e] = redl[0][e]+redl[1][e]+redl[2][e]+redl[3][e];
    float mx = l[0];
    #pragma unroll
    for (int e=1;e<8;e++) mx = fmaxf(mx, l[e]);
    float pp[8], s = 0.f;
    #pragma unroll
    for (int e=0;e<8;e++){ pp[e] = expf(l[e]-mx); s += pp[e]; }
    float inv = 1.f/s;
    #pragma unroll
    for (int e=0;e<8;e++){ pp[e] *= inv; probs_out[(size_t)row*NE + e] = pp[e]; }
    int i1 = 0;
    #pragma unroll
    for (int e=1;e<8;e++) if (pp[e] > pp[i1]) i1 = e;
    int i2 = (i1==0) ? 1 : 0;
    #pragma unroll
    for (int e=0;e<8;e++) if (e != i1 && pp[e] > pp[i2]) i2 = e;
    int pos = atomicAdd(&counts[i1], 1);
    tok_list[i1*NTOK+pos] = row;              // slot 0
    w_list[i1*NTOK+pos] = pp[i1];
    pos = atomicAdd(&counts[i2], 1);
    tok_list[i2*NTOK+pos] = row | (1<<16);    // slot 1
    w_list[i2*NTOK+pos] = pp[i2];
  }
}

// ---------------- MoE grouped GEMM1: mid = gelu(h @ We1[e]^T) ----------------
// grid x = n-tiles, y = m-tiles (ROUND-9 PROVEN). bases inline from counts.
__global__ __launch_bounds__(256) void moe_gemm1_kernel(
    const short* __restrict__ h, const short* __restrict__ we1t,
    const int* __restrict__ tok_list, const int* __restrict__ counts,
    short* __restrict__ mid)
{
  int e = blockIdx.z;
  int cnt = counts[e];
  int m0 = blockIdx.y*128, n0 = blockIdx.x*128;
  if (m0 >= cnt) return;
  int base = 0;
  for (int j=0;j<NE;j++){ int c = counts[j]; if (j<e) base += c; }
  const short* Bt = we1t + (size_t)e*HIDD*DMODEL;
  const int* tl = tok_list + e*NTOK;
  __shared__ short lsA[128*32];
  __shared__ short lsB[128*32];
  int tid = threadIdx.x, wave = tid>>6, lane = tid&63;
  int li = lane&15, g = lane>>4;
  int wm = (wave>>1)*64, wn = (wave&1)*64;
  int srow = wave*32 + (lane>>2), scol = (lane&3)*8;
  const short* gA[2]; const short* gB[2];
  #pragma unroll
  for (int i=0;i<2;i++){
    int rr = min(m0+srow+i*16, cnt-1);
    gA[i] = h + (size_t)(tl[rr] & 0xFFFF)*DMODEL + scol;
    gB[i] = Bt + (size_t)(n0+srow+i*16)*DMODEL + scol;
  }
  f32x4 acc[4][4] = {};
  for (int k0=0; k0<DMODEL; k0+=32){
    #pragma unroll
    for (int i=0;i<2;i++){
      gl_lds16(gA[i]+k0, &lsA[(wave*32+i*16)*32]);
      gl_lds16(gB[i]+k0, &lsB[(wave*32+i*16)*32]);
    }
    __syncthreads();
    bf16x8 af[4], bfr[4];
    #pragma unroll
    for (int m=0;m<4;m++) af[m] = *(bf16x8*)&lsA[(wm+m*16+li)*32 + g*8];
    #pragma unroll
    for (int n=0;n<4;n++) bfr[n] = *(bf16x8*)&lsB[(wn+n*16+li)*32 + g*8];
    #pragma unroll
    for (int m=0;m<4;m++)
      #pragma unroll
      for (int n=0;n<4;n++)
        acc[m][n] = __builtin_amdgcn_mfma_f32_16x16x32_bf16(af[m], bfr[n], acc[m][n], 0,0,0);
    __syncthreads();
  }
  #pragma unroll
  for (int m=0;m<4;m++){
    int lr0 = wm + m*16 + (g<<2);
    #pragma unroll
    for (int n=0;n<4;n++){
      int col = n0 + wn + n*16 + li;
      #pragma unroll
      for (int r=0;r<4;r++){
        int gr = m0 + lr0 + r;
        if (gr < cnt){
          float tval = acc[m][n][r];
          float u = 1.5957691216057308f*(tval + 0.044715f*tval*tval*tval);
          float ge = tval / (1.f + __expf(-u));
          mid[(size_t)(base+gr)*HIDD + col] = f2b(ge);
        }
      }
    }
  }
}

// ---------------- MoE grouped GEMM2: eo[slot][tok] = w*(mid @ We2[e]^T) ----------------
__global__ __launch_bounds__(256) void moe_gemm2_kernel(
    const short* __restrict__ mid, const short* __restrict__ we2t,
    const int* __restrict__ tok_list, const float* __restrict__ w_list,
    const int* __restrict__ counts, float* __restrict__ eo)
{
  int e = blockIdx.z;
  int cnt = counts[e];
  int m0 = blockIdx.y*128, n0 = blockIdx.x*128;
  if (m0 >= cnt) return;
  int base = 0;
  for (int j=0;j<NE;j++){ int c = counts[j]; if (j<e) base += c; }
  const short* A  = mid + (size_t)base*HIDD;
  const short* Bt = we2t + (size_t)e*DMODEL*HIDD;
  const int* tl = tok_list + e*NTOK;
  const float* wl = w_list + e*NTOK;
  __shared__ short lsA[128*32];
  __shared__ short lsB[128*32];
  int tid = threadIdx.x, wave = tid>>6, lane = tid&63;
  int li = lane&15, g = lane>>4;
  int wm = (wave>>1)*64, wn = (wave&1)*64;
  int srow = wave*32 + (lane>>2), scol = (lane&3)*8;
  const short* gA[2]; const short* gB[2];
  #pragma unroll
  for (int i=0;i<2;i++){
    int rr = min(m0+srow+i*16, cnt-1);
    gA[i] = A + (size_t)rr*HIDD + scol;
    gB[i] = Bt + (size_t)(n0+srow+i*16)*HIDD + scol;
  }
  f32x4 acc[4][4] = {};
  for (int k0=0; k0<HIDD; k0+=32){
    #pragma unroll
    for (int i=0;i<2;i++){
      gl_lds16(gA[i]+k0, &lsA[(wave*32+i*16)*32]);
      gl_lds16(gB[i]+k0, &lsB[(wave*32+i*16)*32]);
    }
    __syncthreads();
    bf16x8 af[4], bfr[4];
    #pragma unroll
    for (int m=0;m<4;m++) af[m] = *(bf16x8*)&lsA[(wm+m*16+li)*32 + g*8];
    #pragma unroll
    for (int n=0;n<4;n++) bfr[n] = *(bf16x8*)&lsB[(wn+n*16+li)*32 + g*8];
    #pragma unroll
    for (int m=0;m<4;m++)
      #pragma unroll
      for (int n=0;n<4;n++)
        acc[m][n] = __builtin_amdgcn_mfma_f32_16x16x32_bf16(af[m], bfr[n], acc[m][n], 0,0,0);
    __syncthreads();
  }
  #pragma unroll
  for (int m=0;m<4;m++){
    int lr0 = wm + m*16 + (g<<2);
    #pragma unroll
    for (int n=0;n<4;n++){
      int col = n0 + wn + n*16 + li;
      #pragma unroll
      for (int r=0;r<4;r++){
        int gr = m0 + lr0 + r;
        if (gr < cnt){
          int pv = tl[gr];
          eo[((size_t)(pv>>16)*NTOK + (pv & 0xFFFF))*DMODEL + col] = wl[gr]*acc[m][n][r];
        }
      }
    }
  }
}

// ---------------- out = x2 + rmsnorm(eo0+eo1)*g_post_moe ----------------
__global__ __launch_bounds__(256) void final_kernel(
    const float* __restrict__ x2, const float* __restrict__ eo,
    const float* __restrict__ g, float* __restrict__ out)
{
  int row = blockIdx.x, tid = threadIdx.x;
  float4 m0 = ((const float4*)(eo + (size_t)row*DMODEL))[tid];
  float4 m1 = ((const float4*)(eo + (size_t)(NTOK+row)*DMODEL))[tid];
  float4 mv;
  mv.x = m0.x+m1.x; mv.y = m0.y+m1.y; mv.z = m0.z+m1.z; mv.w = m0.w+m1.w;
  float4 xv = ((const float4*)(x2  + (size_t)row*DMODEL))[tid];
  float ss = mv.x*mv.x + mv.y*mv.y + mv.z*mv.z + mv.w*mv.w;
  #pragma unroll
  for (int off=32; off; off>>=1) ss += __shfl_down(ss, off);
  __shared__ float red[4];
  if ((tid&63)==0) red[tid>>6] = ss;
  __syncthreads();
  float rs = rsqrtf((red[0]+red[1]+red[2]+red[3])*(1.f/1024.f) + EPSV);
  float4 gv = ((const float4*)g)[tid];
  float4 o;
  o.x = xv.x + mv.x*rs*gv.x; o.y = xv.y + mv.y*rs*gv.y;
  o.z = xv.z + mv.z*rs*gv.z; o.w = xv.w + mv.w*rs*gv.w;
  ((float4*)(out + (size_t)row*DMODEL))[tid] = o;
}

extern "C" void kernel_launch(void* const* d_in, const int* in_sizes, int n_in,
                              void* d_out, int out_size, void* d_ws, size_t ws_size,
                              hipStream_t stream) {
  (void)in_sizes; (void)n_in; (void)out_size; (void)ws_size;
  const float* x          = (const float*)d_in[0];
  const float* g_pre_mqa  = (const float*)d_in[1];
  const float* g_post_mqa = (const float*)d_in[2];
  const float* g_pre_moe  = (const float*)d_in[3];
  const float* g_post_moe = (const float*)d_in[4];
  const float* Wq         = (const float*)d_in[5];
  const float* Wk         = (const float*)d_in[6];
  const float* Wv         = (const float*)d_in[7];
  const float* Wo         = (const float*)d_in[8];
  const float* Wg         = (const float*)d_in[9];
  const float* We1        = (const float*)d_in[10];
  const float* We2        = (const float*)d_in[11];

  float* out_x = (float*)d_out;
  float* out_probs = out_x + (size_t)NTOK*DMODEL;

  char* p = (char*)d_ws;
  size_t off = 0;
  auto alloc = [&](size_t bytes)->char*{
    char* r = p + off; off = (off + bytes + 255) & ~(size_t)255; return r; };

  short* we1t = (short*)alloc((size_t)NE*HIDD*DMODEL*2);       // 64M
  short* we2t = (short*)alloc((size_t)NE*DMODEL*HIDD*2);       // 64M
  short* mid  = (short*)alloc((size_t)2*NTOK*HIDD*2);          // 64M

  // region A: xn1 fp16 planes (2x8.4M), later ao fp32 (16.8M)
  char* regA = alloc((size_t)2*NTOK*DMODEL*2);
  _Float16* xn1p1 = (_Float16*)regA;
  _Float16* xn1p2 = (_Float16*)(regA + (size_t)NTOK*DMODEL*2);
  float* ao       = (float*)regA;

  _Float16* wqkvT1 = (_Float16*)alloc((size_t)QKVW*DMODEL*2);
  _Float16* wqkvT2 = (_Float16*)alloc((size_t)QKVW*DMODEL*2);
  _Float16* woT1   = (_Float16*)alloc((size_t)DMODEL*DMODEL*2);
  _Float16* woT2   = (_Float16*)alloc((size_t)DMODEL*DMODEL*2);

  // region B: attn fp16 planes (2x8.4M)
  char* regB = alloc((size_t)2*NTOK*DMODEL*2);
  _Float16* attnp1 = (_Float16*)regB;
  _Float16* attnp2 = (_Float16*)(regB + (size_t)NTOK*DMODEL*2);

  // region C: qkvf fp16 planes (2x9.4M=18.9M), later eo fp32 2 slabs (33.6M) + hbuf (8.4M)
  char* regC = alloc((size_t)2*NTOK*DMODEL*4 + (size_t)NTOK*DMODEL*2);
  _Float16* qkvf1 = (_Float16*)regC;
  _Float16* qkvf2 = (_Float16*)(regC + (size_t)NTOK*QKVW*2);
  float* eo    = (float*)regC;
  short* hbuf  = (short*)(regC + (size_t)2*NTOK*DMODEL*4);

  _Float16* vt1 = (_Float16*)alloc((size_t)2*HDIM*SEQL*2);
  _Float16* vt2 = (_Float16*)alloc((size_t)2*HDIM*SEQL*2);
  float* x2  = (float*)alloc((size_t)NTOK*DMODEL*4);
  int*   tok_l  = (int*)  alloc((size_t)NE*NTOK*4);
  float* w_l    = (float*)alloc((size_t)NE*NTOK*4);
  int*   counts = (int*)  alloc(256);

  // ---- weights prep ----
  transpose_conv_kernel<<<dim3(HIDD/32, DMODEL/32, NE), 256, 0, stream>>>(
      We1, we1t, DMODEL, HIDD, (long)DMODEL*HIDD, (long)HIDD*DMODEL);
  transpose_conv_kernel<<<dim3(DMODEL/32, HIDD/32, NE), 256, 0, stream>>>(
      We2, we2t, HIDD, DMODEL, (long)HIDD*DMODEL, (long)DMODEL*HIDD);
  transpose_split2f16_kernel<<<dim3(DMODEL/32, DMODEL/32), 256, 0, stream>>>(
      Wq, wqkvT1, wqkvT2, DMODEL, DMODEL, 0, DMODEL);
  transpose_split2f16_kernel<<<dim3(HDIM/32, DMODEL/32), 256, 0, stream>>>(
      Wk, wqkvT1, wqkvT2, DMODEL, HDIM, DMODEL, DMODEL);
  transpose_split2f16_kernel<<<dim3(HDIM/32, DMODEL/32), 256, 0, stream>>>(
      Wv, wqkvT1, wqkvT2, DMODEL, HDIM, DMODEL+HDIM, DMODEL);
  transpose_split2f16_kernel<<<dim3(DMODEL/32, DMODEL/32), 256, 0, stream>>>(
      Wo, woT1, woT2, DMODEL, DMODEL, 0, DMODEL);

  // ---- pre-router chain: fp16x2 GEMMs (r9 grid order) + fp16 attention ----
  rms_split2_kernel<<<NTOK, 256, 0, stream>>>(x, g_pre_mqa, xn1p1, xn1p2);
  gemm_f16x2s_kernel<<<dim3(QKVW/128, NTOK/128), 256, 0, stream>>>(
      xn1p1, xn1p2, wqkvT1, wqkvT2, qkvf1, qkvf2, DMODEL, QKVW, OUTSCL*ASCL);
  vtrans_split2_kernel<<<dim3(SEQL/32, HDIM/32, 2), 256, 0, stream>>>(qkvf1, qkvf2, vt1, vt2);
  attn_f16_kernel<<<dim3(SEQL/128, NH, 2), 256, 0, stream>>>(
      qkvf1, qkvf2, vt1, vt2, attnp1, attnp2);
  gemm_f16x2_kernel<<<dim3(DMODEL/128, NTOK/128), 256, 0, stream>>>(
      attnp1, attnp2, woT1, woT2, ao, DMODEL, DMODEL, OUTSCL);

  // ---- fused residual+rmsnorm+router, then grouped MoE (r9 grid order) ----
  hipMemsetAsync(counts, 0, 32, stream);
  attnres_router_kernel<<<NTOK, 256, 0, stream>>>(
      x, ao, g_post_mqa, g_pre_moe, Wg, x2, hbuf, out_probs, tok_l, w_l, counts);
  moe_gemm1_kernel<<<dim3(HIDD/128, NTOK/128, NE), 256, 0, stream>>>(
      hbuf, we1t, tok_l, counts, mid);
  moe_gemm2_kernel<<<dim3(DMODEL/128, NTOK/128, NE), 256, 0, stream>>>(
      mid, we2t, tok_l, w_l, counts, eo);
  final_kernel<<<NTOK, 256, 0, stream>>>(x2, eo, g_post_moe, out_x);
}